// Round 11
// baseline (884.451 us; speedup 1.0000x reference)
//
#include <hip/hip_runtime.h>
#include <hip/hip_bf16.h>
#include <math.h>

// ---- problem constants ----
#define T_TOK  4096      // B*S tokens
#define H_DIM  1024
#define E_NUM  8
#define FF_DIM 4096
#define KSEL   2
#define SLOTS  (T_TOK*KSEL)     // 8192
#define SLOTS_PAD (SLOTS + 256)
#define BM 128
#define MAXTILES 72             // 128-row tiles (18 bands of 4)

typedef __attribute__((ext_vector_type(8))) short s16x8;
typedef __attribute__((ext_vector_type(8))) unsigned short u16x8;
typedef __attribute__((ext_vector_type(4))) float f32x4;

__device__ __forceinline__ unsigned short f2bf(float f){
  unsigned int u = __float_as_uint(f);
  u += 0x7fffu + ((u>>16)&1u);
  return (unsigned short)(u>>16);
}
__device__ __forceinline__ float bf2f(unsigned short h){
  return __uint_as_float(((unsigned int)h)<<16);
}

// ---- workspace layout ----
static constexpr size_t OFF_CNT   = 0;
static constexpr size_t OFF_OFFS  = 256;
static constexpr size_t OFF_NT    = 512;
static constexpr size_t OFF_TILES = 768;
static constexpr size_t OFF_IDX   = 1280;
static constexpr size_t OFF_POS   = OFF_IDX  + 32768;
static constexpr size_t OFF_WV    = OFF_POS  + 32768;
static constexpr size_t OFF_TOK   = OFF_WV   + 32768;
static constexpr size_t OFF_WOF   = OFF_TOK  + 32768;
static constexpr size_t OFF_XG    = OFF_WOF  + 32768;                       // [SLOTS_PAD][H] bf16
static constexpr size_t OFF_W1T   = OFF_XG  + (size_t)SLOTS_PAD*H_DIM*2;    // [E][FF][H] bf16
static constexpr size_t OFF_W2T   = OFF_W1T + (size_t)E_NUM*H_DIM*FF_DIM*2; // [E][H][FF] bf16
static constexpr size_t OFF_MID   = OFF_W2T + (size_t)E_NUM*H_DIM*FF_DIM*2; // [SLOTS_PAD][FF] bf16

// ---- gating: 4 tokens per block ----
__global__ __launch_bounds__(64) void gate_kernel(
    const float* __restrict__ x, const float* __restrict__ Wg,
    const float* __restrict__ bg, int* __restrict__ cnt,
    int* __restrict__ idxp, int* __restrict__ posp, float* __restrict__ wvp)
{
  int lane = threadIdx.x;
  for (int tt=0; tt<4; ++tt){
    int t = blockIdx.x*4 + tt;
    const float* xr = x + (size_t)t*H_DIM;
    float acc[E_NUM];
    #pragma unroll
    for (int e=0;e<E_NUM;e++) acc[e]=0.f;
    for (int i=0;i<H_DIM/64;i++){
      int h = i*64 + lane;
      float xv = xr[h];
      const float* wr_ = Wg + (size_t)h*E_NUM;
      #pragma unroll
      for (int e=0;e<E_NUM;e++) acc[e] += xv*wr_[e];
    }
    #pragma unroll
    for (int e=0;e<E_NUM;e++){
      #pragma unroll
      for (int off=32; off>0; off>>=1) acc[e] += __shfl_xor(acc[e], off);
    }
    if (lane==0){
      float l[E_NUM];
      #pragma unroll
      for (int e=0;e<E_NUM;e++) l[e] = acc[e] + bg[e];
      int i0 = 0;
      #pragma unroll
      for (int e=1;e<E_NUM;e++) if (l[e] > l[i0]) i0 = e;
      int i1 = (i0==0)?1:0;
      #pragma unroll
      for (int e=0;e<E_NUM;e++) if (e!=i0 && l[e] > l[i1]) i1 = e;
      float p1 = expf(l[i1]-l[i0]);
      float s  = 1.f + p1;
      float w0 = 1.f/s, w1 = p1/s;
      int pos0 = atomicAdd(&cnt[i0],1);
      int pos1 = atomicAdd(&cnt[i1],1);
      idxp[t*2]=i0; idxp[t*2+1]=i1;
      posp[t*2]=pos0; posp[t*2+1]=pos1;
      wvp[t*2]=w0; wvp[t*2+1]=w1;
    }
  }
}

// ---- plan ----
__global__ void plan_kernel(const int* __restrict__ cnt, int* __restrict__ offs,
                            int* __restrict__ tiles, int* __restrict__ ntiles)
{
  int o=0, n=0;
  for (int e=0;e<E_NUM;e++){
    offs[e]=o;
    int c=cnt[e];
    int nt=(c+BM-1)/BM;
    for (int m=0;m<nt;m++) tiles[n++] = (e<<16)|m;
    o+=c;
  }
  offs[E_NUM]=o;
  *ntiles=n;
}

// ---- scatter ----
__global__ void scatter_kernel(const int* __restrict__ idxp, const int* __restrict__ posp,
                               const float* __restrict__ wvp, const int* __restrict__ offs,
                               int* __restrict__ tok_of, float* __restrict__ w_of)
{
  int i = blockIdx.x*blockDim.x + threadIdx.x;
  if (i >= SLOTS) return;
  int t = i>>1, k = i&1;
  int e = idxp[t*2+k];
  int slot = offs[e] + posp[t*2+k];
  tok_of[slot] = t;
  w_of[slot]   = wvp[t*2+k];
}

// ---- gather ----
__global__ __launch_bounds__(256) void gather_kernel(
    const float* __restrict__ x, const int* __restrict__ tok_of,
    unsigned short* __restrict__ Xg)
{
  int slot = blockIdx.x;
  int t = tok_of[slot];
  const float4* src = (const float4*)(x + (size_t)t*H_DIM);
  float4 v = src[threadIdx.x];
  ushort4 o;
  o.x=f2bf(v.x); o.y=f2bf(v.y); o.z=f2bf(v.z); o.w=f2bf(v.w);
  ((ushort4*)(Xg + (size_t)slot*H_DIM))[threadIdx.x] = o;
}

// ---- transpose + convert ----
__global__ __launch_bounds__(256) void transconv_kernel(
    const float* __restrict__ in, unsigned short* __restrict__ out, int R, int C)
{
  __shared__ float tile[64][65];
  int e = blockIdx.z;
  const float* inp = in + (size_t)e*R*C;
  unsigned short* op = out + (size_t)e*R*C;
  int c0 = blockIdx.x*64, r0 = blockIdx.y*64;
  int tx = threadIdx.x & 15, ty = threadIdx.x >> 4;
  #pragma unroll
  for (int i=0;i<4;i++){
    int r = i*16 + ty;
    float4 v = *(const float4*)(inp + (size_t)(r0+r)*C + c0 + tx*4);
    tile[r][tx*4+0]=v.x; tile[r][tx*4+1]=v.y; tile[r][tx*4+2]=v.z; tile[r][tx*4+3]=v.w;
  }
  __syncthreads();
  int wx = threadIdx.x & 7;
  int wcl = threadIdx.x >> 3;
  #pragma unroll
  for (int i=0;i<2;i++){
    int c = i*32 + wcl;
    u16x8 o;
    #pragma unroll
    for (int j=0;j<8;j++) o[j] = f2bf(tile[wx*8+j][c]);
    *(u16x8*)(op + (size_t)(c0+c)*R + r0 + wx*8) = o;
  }
}

// ==== grouped GEMM, BARRIER-FREE: no LDS, fragments loaded global->reg.
// 128x128 tile, 4 waves, wave-tile 64x64; each wave an independent pipeline
// (ping-pong register prefetch 1 K-step ahead, compiler-managed waits).
// Chunked XCD mapping (r8: best FETCH). MODE 0: gelu -> bf16 mid.
// MODE 1: gate-scale + fp32 atomicAdd into out (2 commutative adds/elem ->
// bitwise deterministic). ====
template<int MODE>
__global__ __launch_bounds__(256) void gemmng_kernel(
    const unsigned short* __restrict__ A,    // [rows][K]
    const unsigned short* __restrict__ Bt,   // [E][N][K]
    const float* __restrict__ bias,          // [E][N]
    unsigned short* __restrict__ Out,        // MODE0: mid [rows][N]
    float* __restrict__ OutF,                // MODE1: out [T][H]
    const int* __restrict__ tok_of,
    const int* __restrict__ tiles, const int* __restrict__ ntiles,
    const int* __restrict__ cnt, const int* __restrict__ offs,
    const float* __restrict__ w_of,
    int N, int K, int cpcs)                  // cpcs: log2(col-bands)
{
  // chunked mapping: chunk = 4 tiles x 4 col-blocks pinned to XCD blockIdx&7
  int L = blockIdx.x;
  int xcd = L & 7;
  int slot = L >> 3;
  int within = slot & 15;
  int chunk = ((slot >> 4) << 3) + xcd;
  int tb = chunk >> cpcs;
  int cb = chunk & ((1<<cpcs)-1);
  int tile_id = tb*4 + (within & 3);
  if (tile_id >= *ntiles) return;
  int col0 = (cb*4 + (within >> 2)) << 7;

  int packed = tiles[tile_id];
  int e = packed>>16, mt = packed & 0xffff;
  int row0 = offs[e] + mt*BM;
  int nvalid = cnt[e] - mt*BM; if (nvalid > BM) nvalid = BM;
  const unsigned short* Be = Bt + (size_t)e*N*K;

  int t = threadIdx.x;
  int wid = t>>6, lane = t&63;
  int wr = (wid>>1)*64, wc = (wid&1)*64;
  int fr = lane&15, fq = lane>>4;

  // per-lane fragment base pointers: row (base+i*16+fr), k-chunk fq*8
  const unsigned short* pa = A  + (size_t)(row0 + wr + fr)*K + fq*8;
  const unsigned short* pb = Be + (size_t)(col0 + wc + fr)*K + fq*8;

  f32x4 acc[4][4];
  #pragma unroll
  for (int i=0;i<4;i++)
    #pragma unroll
    for (int j=0;j<4;j++) acc[i][j] = (f32x4){0.f,0.f,0.f,0.f};

  s16x8 a0[4], b0[4], a1[4], b1[4];

#define LDF(da, db, kk) do{ \
    _Pragma("unroll") \
    for (int i=0;i<4;i++){ \
      da[i] = *(const s16x8*)(pa + (size_t)i*16*K + (kk)); \
      db[i] = *(const s16x8*)(pb + (size_t)i*16*K + (kk)); \
    } }while(0)
#define MMF(aa, bb) do{ \
    _Pragma("unroll") \
    for (int i=0;i<4;i++) \
      _Pragma("unroll") \
      for (int j=0;j<4;j++) \
        acc[i][j] = __builtin_amdgcn_mfma_f32_16x16x32_bf16(aa[i], bb[j], acc[i][j], 0,0,0); \
    }while(0)

  int NT = K >> 5;                  // K-steps of 32 (NT is even: 32 or 128)
  LDF(a0, b0, 0);
  for (int kt=0; kt<NT; kt+=2){
    if (kt+1 < NT) LDF(a1, b1, (size_t)(kt+1)*32);
    MMF(a0, b0);
    if (kt+2 < NT) LDF(a0, b0, (size_t)(kt+2)*32);
    if (kt+1 < NT) MMF(a1, b1);
  }
#undef LDF
#undef MMF

  // epilogue: C/D layout col=lane&15, row=(lane>>4)*4+reg
  #pragma unroll
  for (int i=0;i<4;i++){
    #pragma unroll
    for (int r=0;r<4;r++){
      int lrow = wr + i*16 + fq*4 + r;
      if (lrow < nvalid){
        int grow = row0 + lrow;
        if (MODE==0){
          #pragma unroll
          for (int j=0;j<4;j++){
            int col = col0 + wc + j*16 + fr;
            float v = acc[i][j][r] + bias[(size_t)e*N + col];
            v = 0.5f*v*(1.f + erff(v*0.70710678118654752f));
            Out[(size_t)grow*N + col] = f2bf(v);
          }
        } else {
          int tok = tok_of[grow];
          float scale = w_of[grow];
          #pragma unroll
          for (int j=0;j<4;j++){
            int col = col0 + wc + j*16 + fr;
            float v = (acc[i][j][r] + bias[(size_t)e*N + col]) * scale;
            atomicAdd(&OutF[(size_t)tok*H_DIM + col], v);
          }
        }
      }
    }
  }
}

extern "C" void kernel_launch(void* const* d_in, const int* in_sizes, int n_in,
                              void* d_out, int out_size, void* d_ws, size_t ws_size,
                              hipStream_t stream) {
  const float* x  = (const float*)d_in[0];
  const float* Wg = (const float*)d_in[1];
  const float* bg = (const float*)d_in[2];
  const float* W1 = (const float*)d_in[3];
  const float* b1 = (const float*)d_in[4];
  const float* W2 = (const float*)d_in[5];
  const float* b2 = (const float*)d_in[6];
  float* out = (float*)d_out;
  char* ws = (char*)d_ws;

  int*   cnt      = (int*)  (ws + OFF_CNT);
  int*   offs     = (int*)  (ws + OFF_OFFS);
  int*   ntiles   = (int*)  (ws + OFF_NT);
  int*   tiles    = (int*)  (ws + OFF_TILES);
  int*   idxp     = (int*)  (ws + OFF_IDX);
  int*   posp     = (int*)  (ws + OFF_POS);
  float* wvp      = (float*)(ws + OFF_WV);
  int*   tok_of   = (int*)  (ws + OFF_TOK);
  float* w_of     = (float*)(ws + OFF_WOF);
  unsigned short* Xg  = (unsigned short*)(ws + OFF_XG);
  unsigned short* W1t = (unsigned short*)(ws + OFF_W1T);
  unsigned short* W2t = (unsigned short*)(ws + OFF_W2T);
  unsigned short* mid = (unsigned short*)(ws + OFF_MID);

  hipMemsetAsync(ws + OFF_CNT, 0, 32, stream);
  hipMemsetAsync(d_out, 0, (size_t)out_size*sizeof(float), stream);

  gate_kernel<<<T_TOK/4, 64, 0, stream>>>(x, Wg, bg, cnt, idxp, posp, wvp);
  plan_kernel<<<1, 1, 0, stream>>>(cnt, offs, tiles, ntiles);
  scatter_kernel<<<SLOTS/256, 256, 0, stream>>>(idxp, posp, wvp, offs, tok_of, w_of);
  gather_kernel<<<SLOTS, 256, 0, stream>>>(x, tok_of, Xg);

  transconv_kernel<<<dim3(FF_DIM/64, H_DIM/64, E_NUM), 256, 0, stream>>>(W1, W1t, H_DIM, FF_DIM);
  transconv_kernel<<<dim3(H_DIM/64, FF_DIM/64, E_NUM), 256, 0, stream>>>(W2, W2t, FF_DIM, H_DIM);

  // GEMM1: 18 tile-bands x 8 col-bands = 144 chunks -> 2304 blocks
  gemmng_kernel<0><<<dim3(2304), 256, 0, stream>>>(
      Xg, W1t, b1, mid, nullptr, tok_of, tiles, ntiles, cnt, offs, nullptr,
      FF_DIM, H_DIM, 3);
  // GEMM2: 18 tile-bands x 2 col-bands = 36 chunks -> ceil(36/8)*128 = 640 blocks
  gemmng_kernel<1><<<dim3(640), 256, 0, stream>>>(
      mid, W2t, b2, nullptr, out, tok_of, tiles, ntiles, cnt, offs, w_of,
      H_DIM, FF_DIM, 1);
}

// Round 12
// 480.484 us; speedup vs baseline: 1.8408x; 1.8408x over previous
//
#include <hip/hip_runtime.h>
#include <hip/hip_bf16.h>
#include <math.h>

// ---- problem constants ----
#define T_TOK  4096      // B*S tokens
#define H_DIM  1024
#define E_NUM  8
#define FF_DIM 4096
#define KSEL   2
#define SLOTS  (T_TOK*KSEL)     // 8192
#define SLOTS_PAD (SLOTS + 256)
#define BM 128
#define MAXTILES 72             // 128-row tiles

typedef __attribute__((ext_vector_type(8))) short s16x8;
typedef __attribute__((ext_vector_type(8))) unsigned short u16x8;
typedef __attribute__((ext_vector_type(4))) float f32x4;

typedef __attribute__((address_space(1))) const void global_cvoid;
typedef __attribute__((address_space(3))) void lds_void;

__device__ __forceinline__ unsigned short f2bf(float f){
  unsigned int u = __float_as_uint(f);
  u += 0x7fffu + ((u>>16)&1u);
  return (unsigned short)(u>>16);
}

// ---- workspace layout ----
static constexpr size_t OFF_CNT   = 0;
static constexpr size_t OFF_OFFS  = 256;
static constexpr size_t OFF_NT    = 512;
static constexpr size_t OFF_TILES = 768;
static constexpr size_t OFF_IDX   = 1280;
static constexpr size_t OFF_POS   = OFF_IDX  + 32768;
static constexpr size_t OFF_WV    = OFF_POS  + 32768;
static constexpr size_t OFF_TOK   = OFF_WV   + 32768;   // [SLOTS] int
static constexpr size_t OFF_WOF   = OFF_TOK  + 32768;   // [SLOTS] float
static constexpr size_t OFF_XBF   = OFF_WOF  + 32768;                       // [T][H] bf16
static constexpr size_t OFF_W1T   = OFF_XBF + (size_t)T_TOK*H_DIM*2;        // [E][FF][H] bf16
static constexpr size_t OFF_W2T   = OFF_W1T + (size_t)E_NUM*H_DIM*FF_DIM*2; // [E][H][FF] bf16
static constexpr size_t OFF_MID   = OFF_W2T + (size_t)E_NUM*H_DIM*FF_DIM*2; // [SLOTS_PAD][FF] bf16

// ---- gating: 4 tokens per block (validated r10) ----
__global__ __launch_bounds__(64) void gate_kernel(
    const float* __restrict__ x, const float* __restrict__ Wg,
    const float* __restrict__ bg, int* __restrict__ cnt,
    int* __restrict__ idxp, int* __restrict__ posp, float* __restrict__ wvp)
{
  int lane = threadIdx.x;
  for (int tt=0; tt<4; ++tt){
    int t = blockIdx.x*4 + tt;
    const float* xr = x + (size_t)t*H_DIM;
    float acc[E_NUM];
    #pragma unroll
    for (int e=0;e<E_NUM;e++) acc[e]=0.f;
    for (int i=0;i<H_DIM/64;i++){
      int h = i*64 + lane;
      float xv = xr[h];
      const float* wr_ = Wg + (size_t)h*E_NUM;
      #pragma unroll
      for (int e=0;e<E_NUM;e++) acc[e] += xv*wr_[e];
    }
    #pragma unroll
    for (int e=0;e<E_NUM;e++){
      #pragma unroll
      for (int off=32; off>0; off>>=1) acc[e] += __shfl_xor(acc[e], off);
    }
    if (lane==0){
      float l[E_NUM];
      #pragma unroll
      for (int e=0;e<E_NUM;e++) l[e] = acc[e] + bg[e];
      int i0 = 0;
      #pragma unroll
      for (int e=1;e<E_NUM;e++) if (l[e] > l[i0]) i0 = e;
      int i1 = (i0==0)?1:0;
      #pragma unroll
      for (int e=0;e<E_NUM;e++) if (e!=i0 && l[e] > l[i1]) i1 = e;
      float p1 = expf(l[i1]-l[i0]);
      float s  = 1.f + p1;
      float w0 = 1.f/s, w1 = p1/s;
      int pos0 = atomicAdd(&cnt[i0],1);
      int pos1 = atomicAdd(&cnt[i1],1);
      idxp[t*2]=i0; idxp[t*2+1]=i1;
      posp[t*2]=pos0; posp[t*2+1]=pos1;
      wvp[t*2]=w0; wvp[t*2+1]=w1;
    }
  }
}

// ---- plan ----
__global__ void plan_kernel(const int* __restrict__ cnt, int* __restrict__ offs,
                            int* __restrict__ tiles, int* __restrict__ ntiles)
{
  int o=0, n=0;
  for (int e=0;e<E_NUM;e++){
    offs[e]=o;
    int c=cnt[e];
    int nt=(c+BM-1)/BM;
    for (int m=0;m<nt;m++) tiles[n++] = (e<<16)|m;
    o+=c;
  }
  offs[E_NUM]=o;
  *ntiles=n;
}

// ---- scatter: slot -> (token, gate weight) ----
__global__ void scatter_kernel(const int* __restrict__ idxp, const int* __restrict__ posp,
                               const float* __restrict__ wvp, const int* __restrict__ offs,
                               int* __restrict__ tok_of, float* __restrict__ w_of)
{
  int i = blockIdx.x*blockDim.x + threadIdx.x;
  if (i >= SLOTS) return;
  int t = i>>1, k = i&1;
  int e = idxp[t*2+k];
  int slot = offs[e] + posp[t*2+k];
  tok_of[slot] = t;
  w_of[slot]   = wvp[t*2+k];
}

// ---- x -> bf16, token order (replaces gather; routing moves into GEMM1 staging) ----
__global__ __launch_bounds__(256) void xconv_kernel(
    const float* __restrict__ x, unsigned short* __restrict__ xbf)
{
  size_t i = (size_t)blockIdx.x*256 + threadIdx.x;
  float4 v = ((const float4*)x)[i];
  ushort4 o;
  o.x=f2bf(v.x); o.y=f2bf(v.y); o.z=f2bf(v.z); o.w=f2bf(v.w);
  ((ushort4*)xbf)[i] = o;
}

// ---- transpose + convert ----
__global__ __launch_bounds__(256) void transconv_kernel(
    const float* __restrict__ in, unsigned short* __restrict__ out, int R, int C)
{
  __shared__ float tile[64][65];
  int e = blockIdx.z;
  const float* inp = in + (size_t)e*R*C;
  unsigned short* op = out + (size_t)e*R*C;
  int c0 = blockIdx.x*64, r0 = blockIdx.y*64;
  int tx = threadIdx.x & 15, ty = threadIdx.x >> 4;
  #pragma unroll
  for (int i=0;i<4;i++){
    int r = i*16 + ty;
    float4 v = *(const float4*)(inp + (size_t)(r0+r)*C + c0 + tx*4);
    tile[r][tx*4+0]=v.x; tile[r][tx*4+1]=v.y; tile[r][tx*4+2]=v.z; tile[r][tx*4+3]=v.w;
  }
  __syncthreads();
  int wx = threadIdx.x & 7;
  int wcl = threadIdx.x >> 3;
  #pragma unroll
  for (int i=0;i<2;i++){
    int c = i*32 + wcl;
    u16x8 o;
    #pragma unroll
    for (int j=0;j<8;j++) o[j] = f2bf(tile[wx*8+j][c]);
    *(u16x8*)(op + (size_t)(c0+c)*R + r0 + wx*8) = o;
  }
}

#define GLDS(g, l) __builtin_amdgcn_global_load_lds((global_cvoid*)(g), (lds_void*)(l), 16, 0, 0)

// ==== grouped GEMM (r7 core, unchanged): 128x128, BK=32, 256 thr, dbuf,
// depth-2 counted vmcnt(4), 2-way-max swizzle, launch_bounds(256,4).
// MODE 0: A rows routed via tok_of (from xbf), gelu epilogue -> bf16 mid.
// MODE 1: A rows direct (mid), gate-scale + fp32 atomicAdd into out
// (2 commutative adds/element -> bitwise deterministic). ====
template<int MODE>
__global__ __launch_bounds__(256, 4) void gemm128_kernel(
    const unsigned short* __restrict__ A,    // MODE0: xbf [T][K]; MODE1: mid [rows][K]
    const unsigned short* __restrict__ Bt,   // [E][N][K]
    const float* __restrict__ bias,          // [E][N]
    unsigned short* __restrict__ Out,        // MODE0: mid [rows][N]
    float* __restrict__ OutF,                // MODE1: out [T][H]
    const int* __restrict__ tok_of,
    const int* __restrict__ tiles, const int* __restrict__ ntiles,
    const int* __restrict__ cnt, const int* __restrict__ offs,
    const float* __restrict__ w_of,
    int N, int K, int cshift)
{
  int tile_id = blockIdx.x >> cshift;
  if (tile_id >= *ntiles) return;
  int col0 = (blockIdx.x & ((1<<cshift)-1)) << 7;
  int packed = tiles[tile_id];
  int e = packed>>16, mt = packed & 0xffff;
  int row0 = offs[e] + mt*BM;
  int nvalid = cnt[e] - mt*BM; if (nvalid > BM) nvalid = BM;
  const unsigned short* Be = Bt + (size_t)e*N*K;

  __shared__ unsigned short As[2][128*32];
  __shared__ unsigned short Bs[2][128*32];
  char* asb = (char*)&As[0][0];
  char* bsb = (char*)&Bs[0][0];

  int t = threadIdx.x;
  int wid = t>>6, lane = t&63;
  int wr = (wid>>1)*64, wc = (wid&1)*64;
  int fr = lane&15, fq = lane>>4;

  // staging: thread t -> row t>>2 (+64), phys chunk t&3;
  // source logical chunk scl = (phys - (row>>1))&3 (inverse of read swizzle)
  int srow = t>>2;
  int scl  = ((t&3) - ((t>>3)&3)) & 3;
  int sdst = wid*1024;

  // A row source: MODE0 routes through tok_of (resolved ONCE per thread)
  const unsigned short* pA0;
  const unsigned short* pA1;
  if (MODE==0){
    int r0i = row0 + srow;        if (r0i > SLOTS-1) r0i = SLOTS-1;
    int r1i = row0 + 64 + srow;   if (r1i > SLOTS-1) r1i = SLOTS-1;
    pA0 = A + (size_t)tok_of[r0i]*K + scl*8;
    pA1 = A + (size_t)tok_of[r1i]*K + scl*8;
  } else {
    pA0 = A + (size_t)(row0 + srow)*K      + scl*8;
    pA1 = A + (size_t)(row0 + 64 + srow)*K + scl*8;
  }
  const unsigned short* pB0 = Be + (size_t)(col0 + srow)*K      + scl*8;
  const unsigned short* pB1 = Be + (size_t)(col0 + 64 + srow)*K + scl*8;

  auto stage = [&](int buf, int kelem){
    GLDS(pA0 + kelem, asb + buf*8192 + sdst);
    GLDS(pA1 + kelem, asb + buf*8192 + 4096 + sdst);
    GLDS(pB0 + kelem, bsb + buf*8192 + sdst);
    GLDS(pB1 + kelem, bsb + buf*8192 + 4096 + sdst);
  };

  int rd_sw = ((fq + ((fr>>1)&3)) & 3) << 4;

  f32x4 acc[4][4];
  #pragma unroll
  for (int i=0;i<4;i++)
    #pragma unroll
    for (int j=0;j<4;j++) acc[i][j] = (f32x4){0.f,0.f,0.f,0.f};

  int NT = K >> 5;
  stage(0, 0);
  stage(1, 32);
  for (int kt=0; kt<NT; ++kt){
    int cur = kt&1;
    if (kt+1 < NT) asm volatile("s_waitcnt vmcnt(4)" ::: "memory");
    else           asm volatile("s_waitcnt vmcnt(0)" ::: "memory");
    __builtin_amdgcn_s_barrier();
    asm volatile("" ::: "memory");

    s16x8 af[4], bfr[4];
    #pragma unroll
    for (int i=0;i<4;i++){
      af[i]  = *(const s16x8*)(asb + cur*8192 + (wr + i*16 + fr)*64 + rd_sw);
      bfr[i] = *(const s16x8*)(bsb + cur*8192 + (wc + i*16 + fr)*64 + rd_sw);
    }
    #pragma unroll
    for (int i=0;i<4;i++)
      #pragma unroll
      for (int j=0;j<4;j++)
        acc[i][j] = __builtin_amdgcn_mfma_f32_16x16x32_bf16(af[i], bfr[j], acc[i][j], 0,0,0);

    asm volatile("s_waitcnt lgkmcnt(0)" ::: "memory");
    __builtin_amdgcn_s_barrier();
    asm volatile("" ::: "memory");
    if (kt+2 < NT) stage(cur, (kt+2)*32);
  }

  // epilogue: C/D layout col=lane&15, row=(lane>>4)*4+reg
  #pragma unroll
  for (int i=0;i<4;i++){
    #pragma unroll
    for (int r=0;r<4;r++){
      int lrow = wr + i*16 + fq*4 + r;
      if (lrow < nvalid){
        int grow = row0 + lrow;
        if (MODE==0){
          #pragma unroll
          for (int j=0;j<4;j++){
            int col = col0 + wc + j*16 + fr;
            float v = acc[i][j][r] + bias[(size_t)e*N + col];
            v = 0.5f*v*(1.f + erff(v*0.70710678118654752f));
            Out[(size_t)grow*N + col] = f2bf(v);
          }
        } else {
          int tok = tok_of[grow];
          float scale = w_of[grow];
          #pragma unroll
          for (int j=0;j<4;j++){
            int col = col0 + wc + j*16 + fr;
            float v = (acc[i][j][r] + bias[(size_t)e*N + col]) * scale;
            atomicAdd(&OutF[(size_t)tok*H_DIM + col], v);
          }
        }
      }
    }
  }
}

extern "C" void kernel_launch(void* const* d_in, const int* in_sizes, int n_in,
                              void* d_out, int out_size, void* d_ws, size_t ws_size,
                              hipStream_t stream) {
  const float* x  = (const float*)d_in[0];
  const float* Wg = (const float*)d_in[1];
  const float* bg = (const float*)d_in[2];
  const float* W1 = (const float*)d_in[3];
  const float* b1 = (const float*)d_in[4];
  const float* W2 = (const float*)d_in[5];
  const float* b2 = (const float*)d_in[6];
  float* out = (float*)d_out;
  char* ws = (char*)d_ws;

  int*   cnt      = (int*)  (ws + OFF_CNT);
  int*   offs     = (int*)  (ws + OFF_OFFS);
  int*   ntiles   = (int*)  (ws + OFF_NT);
  int*   tiles    = (int*)  (ws + OFF_TILES);
  int*   idxp     = (int*)  (ws + OFF_IDX);
  int*   posp     = (int*)  (ws + OFF_POS);
  float* wvp      = (float*)(ws + OFF_WV);
  int*   tok_of   = (int*)  (ws + OFF_TOK);
  float* w_of     = (float*)(ws + OFF_WOF);
  unsigned short* xbf = (unsigned short*)(ws + OFF_XBF);
  unsigned short* W1t = (unsigned short*)(ws + OFF_W1T);
  unsigned short* W2t = (unsigned short*)(ws + OFF_W2T);
  unsigned short* mid = (unsigned short*)(ws + OFF_MID);

  hipMemsetAsync(ws + OFF_CNT, 0, 32, stream);
  hipMemsetAsync(d_out, 0, (size_t)out_size*sizeof(float), stream);

  gate_kernel<<<T_TOK/4, 64, 0, stream>>>(x, Wg, bg, cnt, idxp, posp, wvp);
  plan_kernel<<<1, 1, 0, stream>>>(cnt, offs, tiles, ntiles);
  scatter_kernel<<<SLOTS/256, 256, 0, stream>>>(idxp, posp, wvp, offs, tok_of, w_of);
  xconv_kernel<<<(T_TOK*H_DIM/4)/256, 256, 0, stream>>>(x, xbf);

  transconv_kernel<<<dim3(FF_DIM/64, H_DIM/64, E_NUM), 256, 0, stream>>>(W1, W1t, H_DIM, FF_DIM);
  transconv_kernel<<<dim3(H_DIM/64, FF_DIM/64, E_NUM), 256, 0, stream>>>(W2, W2t, FF_DIM, H_DIM);

  // GEMM1: mid = gelu(x[tok] @ W1[e] + b1[e]); routing fused into A-staging
  gemm128_kernel<0><<<dim3(MAXTILES*32), 256, 0, stream>>>(
      xbf, W1t, b1, mid, nullptr, tok_of, tiles, ntiles, cnt, offs, nullptr,
      FF_DIM, H_DIM, 5);
  // GEMM2: out[tok] += (mid @ W2[e] + b2[e]) * gate_w (combine fused)
  gemm128_kernel<1><<<dim3(MAXTILES*8), 256, 0, stream>>>(
      mid, W2t, b2, nullptr, out, tok_of, tiles, ntiles, cnt, offs, w_of,
      H_DIM, FF_DIM, 3);
}